// Round 1
// baseline (286.856 us; speedup 1.0000x reference)
//
#include <hip/hip_runtime.h>
#include <stdint.h>

// Problem shape (fixed by reference): xs [B,T,N,D] fp32, A [1,N,N] int32
#define BB 4
#define TT 32
#define NN 128
#define DD 32
#define NPB 16                       // nodes handled per block
#define NBLK (BB * TT * (NN / NPB))  // 1024 blocks

// monotone bijection float -> sortable u32 (no NaNs in input)
__device__ __forceinline__ uint32_t f2k(float f) {
    uint32_t u = __float_as_uint(f);
    return u ^ (uint32_t)(((int32_t)u >> 31) | 0x80000000u);
}
__device__ __forceinline__ float k2f(uint32_t k) {
    uint32_t u = k ^ (uint32_t)(((int32_t)(~k) >> 31) | 0x80000000u);
    return __uint_as_float(u);
}

// Build per-node compacted neighbor lists from A (+ implicit self loop).
// One wave per node; ballot+popcount compaction. nbr[n][c] = j index, deg[n] = count.
__global__ __launch_bounds__(64) void build_adj_kernel(const int* __restrict__ A,
                                                       int* __restrict__ deg,
                                                       uint8_t* __restrict__ nbr) {
    const int n = blockIdx.x;
    const int lane = threadIdx.x;  // 0..63
    const int* arow = A + n * NN;
    uint8_t* row = nbr + n * NN;
    const int j0 = lane, j1 = lane + 64;
    const bool b0 = (arow[j0] != 0) || (j0 == n);
    const bool b1 = (arow[j1] != 0) || (j1 == n);
    const unsigned long long m0 = __ballot(b0);
    const unsigned long long m1 = __ballot(b1);
    const unsigned long long lmask = (1ULL << lane) - 1ULL;
    const int c0 = __popcll(m0);
    if (b0) row[__popcll(m0 & lmask)] = (uint8_t)j0;
    if (b1) row[c0 + __popcll(m1 & lmask)] = (uint8_t)j1;
    if (lane == 0) deg[n] = c0 + __popcll(m1);
}

__global__ __launch_bounds__(256) void median_kernel(const float* __restrict__ xs,
                                                     const int* __restrict__ deg,
                                                     const uint8_t* __restrict__ nbr,
                                                     float* __restrict__ out) {
    __shared__ uint32_t skey[NN * DD];           // current frame, as sortable keys (16 KB)
    __shared__ uint32_t snbr_w[NPB * NN / 4];    // neighbor lists for this block's nodes (2 KB)
    __shared__ int sdeg[NPB];

    const int tid = threadIdx.x;
    const int g = blockIdx.x;
    const int ng = g % (NN / NPB);
    const int t  = (g / (NN / NPB)) % TT;
    const int b  = g / ((NN / NPB) * TT);
    const int n0 = ng * NPB;

    const float* xcur = xs + ((size_t)(b * TT + t) * NN) * DD;

    // stage current frame -> LDS as keys (coalesced float4 loads, ds_write_b128)
    const float4* src4 = (const float4*)xcur;
    #pragma unroll
    for (int s = 0; s < 4; ++s) {
        int i4 = tid + s * 256;
        float4 v = src4[i4];
        uint4 w;
        w.x = f2k(v.x); w.y = f2k(v.y); w.z = f2k(v.z); w.w = f2k(v.w);
        ((uint4*)skey)[i4] = w;
    }
    // stage neighbor lists (u8 rows, copied as u32)
    const uint32_t* nsrc = (const uint32_t*)(nbr + (size_t)n0 * NN);
    #pragma unroll
    for (int s = 0; s < (NPB * NN / 4) / 256; ++s)
        snbr_w[tid + s * 256] = nsrc[tid + s * 256];
    if (tid < NPB) sdeg[tid] = deg[n0 + tid];
    __syncthreads();

    const int d = tid & (DD - 1);
    const int pv = (t > 0) ? 1 : 0;
    const int nv = (t < TT - 1) ? 1 : 0;

    for (int it = 0; it < NPB / 8; ++it) {
        const int nl = it * 8 + (tid >> 5);  // local node index
        const int n = n0 + nl;
        const int dg = sdeg[nl];
        const int k = dg + pv + nv;
        const int r = (k - 1) >> 1;  // lower-median rank
        uint32_t extra[2]; int ne = 0;
        if (pv) extra[ne++] = f2k(xs[(((size_t)(b * TT + t - 1) * NN) + n) * DD + d]);
        if (nv) extra[ne++] = f2k(xs[(((size_t)(b * TT + t + 1) * NN) + n) * DD + d]);
        const uint8_t* nb = ((const uint8_t*)snbr_w) + nl * NN;

        uint32_t result = 0;
        bool found = false;

        // FAST PATH: strict-< counting; exact when keys in this candidate set are distinct.
        for (int i0 = 0; i0 < k && !found; i0 += 8) {
            uint32_t ki[8], cnt[8];
            #pragma unroll
            for (int u = 0; u < 8; ++u) {
                int i = i0 + u;
                ki[u] = (i < k) ? ((i < dg) ? skey[nb[i] * DD + d] : extra[i - dg])
                                : 0xFFFFFFFFu;
                cnt[u] = 0;
            }
            int j = 0;
            for (; j + 4 <= dg; j += 4) {
                uint32_t nw = *(const uint32_t*)(nb + j);  // 4 neighbor ids at once
                #pragma unroll
                for (int q = 0; q < 4; ++q) {
                    uint32_t kj = skey[((nw >> (8 * q)) & 0xFFu) * DD + d];
                    #pragma unroll
                    for (int u = 0; u < 8; ++u) cnt[u] += (kj < ki[u]) ? 1u : 0u;
                }
            }
            for (; j < dg; ++j) {
                uint32_t kj = skey[nb[j] * DD + d];
                #pragma unroll
                for (int u = 0; u < 8; ++u) cnt[u] += (kj < ki[u]) ? 1u : 0u;
            }
            for (int e = 0; e < ne; ++e) {
                uint32_t kj = extra[e];
                #pragma unroll
                for (int u = 0; u < 8; ++u) cnt[u] += (kj < ki[u]) ? 1u : 0u;
            }
            #pragma unroll
            for (int u = 0; u < 8; ++u) {
                if (!found && (i0 + u) < k && cnt[u] == (uint32_t)r) {
                    result = ki[u];
                    found = true;
                }
            }
        }

        // SAFE PATH (rare: duplicate keys spanning the median rank).
        // Exact torch.median lower-median: found iff cnt_lt <= r < cnt_le.
        if (__ballot(!found)) {
            for (int i0 = 0; i0 < k && !found; i0 += 8) {
                uint32_t ki[8], clt[8], cle[8];
                #pragma unroll
                for (int u = 0; u < 8; ++u) {
                    int i = i0 + u;
                    ki[u] = (i < k) ? ((i < dg) ? skey[nb[i] * DD + d] : extra[i - dg])
                                    : 0xFFFFFFFFu;
                    clt[u] = 0; cle[u] = 0;
                }
                for (int j = 0; j < k; ++j) {
                    uint32_t kj = (j < dg) ? skey[nb[j] * DD + d] : extra[j - dg];
                    #pragma unroll
                    for (int u = 0; u < 8; ++u) {
                        clt[u] += (kj < ki[u]) ? 1u : 0u;
                        cle[u] += (kj <= ki[u]) ? 1u : 0u;
                    }
                }
                #pragma unroll
                for (int u = 0; u < 8; ++u) {
                    if (!found && (i0 + u) < k && clt[u] <= (uint32_t)r && (uint32_t)r < cle[u]) {
                        result = ki[u];
                        found = true;
                    }
                }
            }
        }

        out[(((size_t)(b * TT + t) * NN) + n) * DD + d] = k2f(result);
    }
}

extern "C" void kernel_launch(void* const* d_in, const int* in_sizes, int n_in,
                              void* d_out, int out_size, void* d_ws, size_t ws_size,
                              hipStream_t stream) {
    const float* xs = (const float*)d_in[0];
    const int* A = (const int*)d_in[1];
    float* out = (float*)d_out;

    // workspace layout: deg[128] int (512 B) | nbr[128][128] u8 (16 KB)
    int* deg = (int*)d_ws;
    uint8_t* nbr = (uint8_t*)d_ws + 512;

    build_adj_kernel<<<NN, 64, 0, stream>>>(A, deg, nbr);
    median_kernel<<<NBLK, 256, 0, stream>>>(xs, deg, nbr, out);
}

// Round 2
// 197.172 us; speedup vs baseline: 1.4549x; 1.4549x over previous
//
#include <hip/hip_runtime.h>
#include <stdint.h>

// Problem shape (fixed by reference): xs [B,T,N,D] fp32, A [1,N,N] int32
#define BB 4
#define TT 32
#define NN 128
#define DD 32
#define NPB 8                        // nodes per block (8 nodes x 32 d = 256 threads)
#define NBLK (BB * TT * (NN / NPB))  // 2048 blocks
#define CAP 33                       // per-thread band list capacity (odd -> LDS bank spread)

// Band boundaries in sortable-key space (see f2k): median of ~66 N(0,1) samples
// has std ~0.154, so it is in [-0.8, 0.8] except ~1e-7/output; fallback is exact anyway.
#define KLO 0x40B33332u  // f2k(-0.8f)
#define KMID 0x80000000u // f2k(+0.0f)
#define KHI 0xBF4CCCCDu  // f2k(+0.8f)

// monotone bijection float -> sortable u32 (no NaNs in input)
__device__ __forceinline__ uint32_t f2k(float f) {
    uint32_t u = __float_as_uint(f);
    return u ^ (uint32_t)(((int32_t)u >> 31) | 0x80000000u);
}
__device__ __forceinline__ float k2f(uint32_t k) {
    uint32_t u = k ^ (uint32_t)(((int32_t)(~k) >> 31) | 0x80000000u);
    return __uint_as_float(u);
}

// Build per-node compacted neighbor lists from A (+ implicit self loop).
__global__ __launch_bounds__(64) void build_adj_kernel(const int* __restrict__ A,
                                                       int* __restrict__ deg,
                                                       uint8_t* __restrict__ nbr) {
    const int n = blockIdx.x;
    const int lane = threadIdx.x;  // 0..63
    const int* arow = A + n * NN;
    uint8_t* row = nbr + n * NN;
    const int j0 = lane, j1 = lane + 64;
    const bool b0 = (arow[j0] != 0) || (j0 == n);
    const bool b1 = (arow[j1] != 0) || (j1 == n);
    const unsigned long long m0 = __ballot(b0);
    const unsigned long long m1 = __ballot(b1);
    const unsigned long long lmask = (1ULL << lane) - 1ULL;
    const int c0 = __popcll(m0);
    if (b0) row[__popcll(m0 & lmask)] = (uint8_t)j0;
    if (b1) row[c0 + __popcll(m1 & lmask)] = (uint8_t)j1;
    if (lane == 0) deg[n] = c0 + __popcll(m1);
}

__global__ __launch_bounds__(256) void median_kernel(const float* __restrict__ xs,
                                                     const int* __restrict__ deg,
                                                     const uint8_t* __restrict__ nbr,
                                                     float* __restrict__ out) {
    __shared__ uint32_t skey[NN * DD];          // 16 KB: current frame as keys
    __shared__ uint32_t snbr_w[NPB * NN / 4];   // 1 KB: neighbor lists
    __shared__ int sdeg[NPB];
    __shared__ uint32_t slist[256 * CAP];       // 33 KB: per-thread band lists

    const int tid = threadIdx.x;
    const int g = blockIdx.x;
    const int ng = g % (NN / NPB);
    const int t  = (g / (NN / NPB)) % TT;
    const int b  = g / ((NN / NPB) * TT);
    const int n0 = ng * NPB;

    const float* xcur = xs + ((size_t)(b * TT + t) * NN) * DD;
    const float4* src4 = (const float4*)xcur;
    #pragma unroll
    for (int s = 0; s < 4; ++s) {
        int i4 = tid + s * 256;
        float4 v = src4[i4];
        uint4 w;
        w.x = f2k(v.x); w.y = f2k(v.y); w.z = f2k(v.z); w.w = f2k(v.w);
        ((uint4*)skey)[i4] = w;
    }
    {
        const uint32_t* nsrc = (const uint32_t*)(nbr + (size_t)n0 * NN);
        snbr_w[tid & (NPB * NN / 4 - 1)] = nsrc[tid & (NPB * NN / 4 - 1)];
    }
    if (tid < NPB) sdeg[tid] = deg[n0 + tid];
    __syncthreads();

    const int d = tid & (DD - 1);
    const int pv = (t > 0) ? 1 : 0;
    const int nv = (t < TT - 1) ? 1 : 0;
    uint32_t* mylist = slist + tid * CAP;  // bank(tid*33 + e) = (tid+e)%32: 2-way only

    const int nl = tid >> 5;  // local node 0..7
    const int n = n0 + nl;
    const int dg = sdeg[nl];
    const int k = dg + pv + nv;
    const int r = (k - 1) >> 1;  // lower-median rank (0-based)
    uint32_t extra[2]; int ne = 0;
    if (pv) extra[ne++] = f2k(xs[(((size_t)(b * TT + t - 1) * NN) + n) * DD + d]);
    if (nv) extra[ne++] = f2k(xs[(((size_t)(b * TT + t + 1) * NN) + n) * DD + d]);
    const uint8_t* nb = ((const uint8_t*)snbr_w) + nl * NN;

    // ---- Phase A1: count candidates below the 3 boundaries ----
    uint32_t c1 = 0, c2 = 0, c3 = 0;
    {
        int j = 0;
        for (; j + 4 <= dg; j += 4) {
            uint32_t nw = *(const uint32_t*)(nb + j);
            #pragma unroll
            for (int q = 0; q < 4; ++q) {
                uint32_t kj = skey[((nw >> (8 * q)) & 0xFFu) * DD + d];
                c1 += (kj < KLO) ? 1u : 0u;
                c2 += (kj <= KMID) ? 1u : 0u;
                c3 += (kj <= KHI) ? 1u : 0u;
            }
        }
        for (; j < dg; ++j) {
            uint32_t kj = skey[nb[j] * DD + d];
            c1 += (kj < KLO) ? 1u : 0u;
            c2 += (kj <= KMID) ? 1u : 0u;
            c3 += (kj <= KHI) ? 1u : 0u;
        }
        for (int e = 0; e < ne; ++e) {
            uint32_t kj = extra[e];
            c1 += (kj < KLO) ? 1u : 0u;
            c2 += (kj <= KMID) ? 1u : 0u;
            c3 += (kj <= KHI) ? 1u : 0u;
        }
    }

    // ---- Select sub-band containing rank r ----
    bool fb;              // fallback: median outside band, or band overflows CAP
    uint32_t lo_ex = 1, hi_in = 0;  // default: empty band (stores nothing)
    int rp = 0, mexp = 0;
    if ((uint32_t)r < c1) { fb = true; }
    else if ((uint32_t)r < c2) { fb = false; lo_ex = KLO - 1u; hi_in = KMID; rp = r - (int)c1; mexp = (int)(c2 - c1); }
    else if ((uint32_t)r < c3) { fb = false; lo_ex = KMID;     hi_in = KHI;  rp = r - (int)c2; mexp = (int)(c3 - c2); }
    else { fb = true; }
    if (mexp > CAP) fb = true;
    if (fb) { lo_ex = 1; hi_in = 0; }

    // ---- Phase A2: compact sub-band members into private LDS list ----
    int mc = 0;
    {
        int j = 0;
        for (; j + 4 <= dg; j += 4) {
            uint32_t nw = *(const uint32_t*)(nb + j);
            #pragma unroll
            for (int q = 0; q < 4; ++q) {
                uint32_t kj = skey[((nw >> (8 * q)) & 0xFFu) * DD + d];
                if (kj > lo_ex && kj <= hi_in) { mylist[mc] = kj; ++mc; }
            }
        }
        for (; j < dg; ++j) {
            uint32_t kj = skey[nb[j] * DD + d];
            if (kj > lo_ex && kj <= hi_in) { mylist[mc] = kj; ++mc; }
        }
        for (int e = 0; e < ne; ++e) {
            uint32_t kj = extra[e];
            if (kj > lo_ex && kj <= hi_in) { mylist[mc] = kj; ++mc; }
        }
    }

    // ---- Phase B: rank-rp selection within the m-element list, W=16 counting ----
    uint32_t result = 0;
    bool found = fb;  // fb lanes handled in the fallback below
    for (int i0 = 0; __ballot(!found && i0 < mc); i0 += 16) {
        uint32_t ki[16], cnt[16];
        #pragma unroll
        for (int u = 0; u < 16; ++u) {
            int i = i0 + u;
            ki[u] = (i < mc) ? mylist[i] : 0xFFFFFFFFu;
            cnt[u] = 0;
        }
        for (int j = 0; j < mc; ++j) {
            uint32_t kj = mylist[j];
            #pragma unroll
            for (int u = 0; u < 16; ++u) cnt[u] += (kj < ki[u]) ? 1u : 0u;
        }
        #pragma unroll
        for (int u = 0; u < 16; ++u) {
            // strict-count match is unique across distinct values -> safe whenever it fires
            if (!found && (i0 + u) < mc && cnt[u] == (uint32_t)rp) { result = ki[u]; found = true; }
        }
    }

    // ---- List-safe pass (duplicates inside band; exact multiset lower-median) ----
    if (__ballot(!found && !fb)) {
        for (int i0 = 0; __ballot(!found && i0 < mc); i0 += 8) {
            uint32_t ki[8], clt[8], cle[8];
            #pragma unroll
            for (int u = 0; u < 8; ++u) {
                int i = i0 + u;
                ki[u] = (i < mc) ? mylist[i] : 0xFFFFFFFFu;
                clt[u] = 0; cle[u] = 0;
            }
            for (int j = 0; j < mc; ++j) {
                uint32_t kj = mylist[j];
                #pragma unroll
                for (int u = 0; u < 8; ++u) {
                    clt[u] += (kj < ki[u]) ? 1u : 0u;
                    cle[u] += (kj <= ki[u]) ? 1u : 0u;
                }
            }
            #pragma unroll
            for (int u = 0; u < 8; ++u) {
                if (!found && (i0 + u) < mc && clt[u] <= (uint32_t)rp && (uint32_t)rp < cle[u]) {
                    result = ki[u]; found = true;
                }
            }
        }
    }

    // ---- Full fallback (median outside band / overflow): exact counting over all k ----
    if (__ballot(fb)) {
        bool done = !fb;
        for (int i0 = 0; __ballot(!done && i0 < k); i0 += 8) {
            uint32_t ki[8], cnt[8];
            #pragma unroll
            for (int u = 0; u < 8; ++u) {
                int i = i0 + u;
                ki[u] = (i < k) ? ((i < dg) ? skey[nb[i] * DD + d] : extra[i - dg]) : 0xFFFFFFFFu;
                cnt[u] = 0;
            }
            for (int j = 0; j < dg; ++j) {
                uint32_t kj = skey[nb[j] * DD + d];
                #pragma unroll
                for (int u = 0; u < 8; ++u) cnt[u] += (kj < ki[u]) ? 1u : 0u;
            }
            for (int e = 0; e < ne; ++e) {
                uint32_t kj = extra[e];
                #pragma unroll
                for (int u = 0; u < 8; ++u) cnt[u] += (kj < ki[u]) ? 1u : 0u;
            }
            #pragma unroll
            for (int u = 0; u < 8; ++u) {
                if (!done && (i0 + u) < k && cnt[u] == (uint32_t)r) { result = ki[u]; done = true; }
            }
        }
        if (__ballot(!done)) {  // duplicates across rank: exact multiset selection
            for (int i0 = 0; __ballot(!done && i0 < k); i0 += 4) {
                uint32_t ki[4], clt[4], cle[4];
                #pragma unroll
                for (int u = 0; u < 4; ++u) {
                    int i = i0 + u;
                    ki[u] = (i < k) ? ((i < dg) ? skey[nb[i] * DD + d] : extra[i - dg]) : 0xFFFFFFFFu;
                    clt[u] = 0; cle[u] = 0;
                }
                for (int j = 0; j < k; ++j) {
                    uint32_t kj = (j < dg) ? skey[nb[j] * DD + d] : extra[j - dg];
                    #pragma unroll
                    for (int u = 0; u < 4; ++u) {
                        clt[u] += (kj < ki[u]) ? 1u : 0u;
                        cle[u] += (kj <= ki[u]) ? 1u : 0u;
                    }
                }
                #pragma unroll
                for (int u = 0; u < 4; ++u) {
                    if (!done && (i0 + u) < k && clt[u] <= (uint32_t)r && (uint32_t)r < cle[u]) {
                        result = ki[u]; done = true;
                    }
                }
            }
        }
    }

    out[(((size_t)(b * TT + t) * NN) + n) * DD + d] = k2f(result);
}

extern "C" void kernel_launch(void* const* d_in, const int* in_sizes, int n_in,
                              void* d_out, int out_size, void* d_ws, size_t ws_size,
                              hipStream_t stream) {
    const float* xs = (const float*)d_in[0];
    const int* A = (const int*)d_in[1];
    float* out = (float*)d_out;

    // workspace layout: deg[128] int (512 B) | nbr[128][128] u8 (16 KB)
    int* deg = (int*)d_ws;
    uint8_t* nbr = (uint8_t*)d_ws + 512;

    build_adj_kernel<<<NN, 64, 0, stream>>>(A, deg, nbr);
    median_kernel<<<NBLK, 256, 0, stream>>>(xs, deg, nbr, out);
}